// Round 1
// baseline (1211.239 us; speedup 1.0000x reference)
//
#include <hip/hip_runtime.h>
#include <cstdint>
#include <cstddef>

#define NNODES 20000
#define NEDGES 320000
#define NBATCH 64
#define EPRIME (NEDGES + NNODES)

// ---------------------------------------------------------------- CSR build
__global__ __launch_bounds__(256) void count_kernel(const int* __restrict__ ei,
                                                    int* __restrict__ cnt) {
    int k = blockIdx.x * 256 + threadIdx.x;
    if (k >= EPRIME) return;
    int dst = (k < NEDGES) ? ei[NEDGES + k] : (k - NEDGES);
    atomicAdd(&cnt[dst], 1);
}

__global__ __launch_bounds__(256) void scan_kernel(const int* __restrict__ cnt,
                                                   int* __restrict__ row_ptr,
                                                   int* __restrict__ fillp) {
    __shared__ int buf[256];
    __shared__ int carry;
    int t = threadIdx.x;
    if (t == 0) carry = 0;
    __syncthreads();
    for (int base = 0; base < NNODES; base += 256) {
        int v = (base + t < NNODES) ? cnt[base + t] : 0;
        buf[t] = v;
        __syncthreads();
        for (int off = 1; off < 256; off <<= 1) {
            int add = (t >= off) ? buf[t - off] : 0;
            __syncthreads();
            buf[t] += add;
            __syncthreads();
        }
        int excl = buf[t] - v;
        if (base + t < NNODES) {
            int rp = carry + excl;
            row_ptr[base + t] = rp;
            fillp[base + t] = rp;
        }
        __syncthreads();
        if (t == 255) carry += buf[255];
        __syncthreads();
    }
    if (t == 0) row_ptr[NNODES] = carry;
}

__global__ __launch_bounds__(256) void fill_kernel(const int* __restrict__ ei,
                                                   int* __restrict__ fillp,
                                                   int* __restrict__ csr_src) {
    int k = blockIdx.x * 256 + threadIdx.x;
    if (k >= EPRIME) return;
    int src, dst;
    if (k < NEDGES) { src = ei[k]; dst = ei[NEDGES + k]; }
    else            { src = k - NEDGES; dst = src; }
    int pos = atomicAdd(&fillp[dst], 1);
    csr_src[pos] = src;
}

// ---------------------------------------------------------------- fp32 GEMM
// C[M,Nn] = A[M,K] @ B[K,Nn].  64x64 tile, BK=32, 256 threads, 4x4/thread.
__global__ __launch_bounds__(256) void gemm_kernel(const float* __restrict__ A,
                                                   const float* __restrict__ B,
                                                   float* __restrict__ C,
                                                   int M, int K, int Nn) {
    __shared__ float As[32][65];   // transposed, +1 pad kills store conflicts
    __shared__ float Bs[32][64];
    int t  = threadIdx.x;
    int bm = blockIdx.x * 64;
    int bn = blockIdx.y * 64;
    int tx = t % 16, ty = t / 16;
    float acc[4][4] = {};
    int am0 = t / 8;            // 0..31
    int ak0 = (t % 8) * 4;      // 0..28 step 4
    int bk0 = t / 16;           // 0..15
    int bn0 = (t % 16) * 4;

    for (int k0 = 0; k0 < K; k0 += 32) {
        float4 a0 = make_float4(0.f, 0.f, 0.f, 0.f);
        float4 a1 = make_float4(0.f, 0.f, 0.f, 0.f);
        int r0 = bm + am0, r1 = bm + am0 + 32;
        if (r0 < M) a0 = *(const float4*)&A[r0 * K + k0 + ak0];
        if (r1 < M) a1 = *(const float4*)&A[r1 * K + k0 + ak0];
        float4 b0  = *(const float4*)&B[(k0 + bk0) * Nn + bn + bn0];
        float4 b1v = *(const float4*)&B[(k0 + bk0 + 16) * Nn + bn + bn0];
        __syncthreads();
        As[ak0 + 0][am0] = a0.x; As[ak0 + 1][am0] = a0.y;
        As[ak0 + 2][am0] = a0.z; As[ak0 + 3][am0] = a0.w;
        As[ak0 + 0][am0 + 32] = a1.x; As[ak0 + 1][am0 + 32] = a1.y;
        As[ak0 + 2][am0 + 32] = a1.z; As[ak0 + 3][am0 + 32] = a1.w;
        *(float4*)&Bs[bk0][bn0]      = b0;
        *(float4*)&Bs[bk0 + 16][bn0] = b1v;
        __syncthreads();
#pragma unroll
        for (int kk = 0; kk < 32; kk++) {
            float4 av = *(float4*)&As[kk][ty * 4];
            float4 bv = *(float4*)&Bs[kk][tx * 4];
            acc[0][0] += av.x * bv.x; acc[0][1] += av.x * bv.y;
            acc[0][2] += av.x * bv.z; acc[0][3] += av.x * bv.w;
            acc[1][0] += av.y * bv.x; acc[1][1] += av.y * bv.y;
            acc[1][2] += av.y * bv.z; acc[1][3] += av.y * bv.w;
            acc[2][0] += av.z * bv.x; acc[2][1] += av.z * bv.y;
            acc[2][2] += av.z * bv.z; acc[2][3] += av.z * bv.w;
            acc[3][0] += av.w * bv.x; acc[3][1] += av.w * bv.y;
            acc[3][2] += av.w * bv.z; acc[3][3] += av.w * bv.w;
        }
    }
#pragma unroll
    for (int i = 0; i < 4; i++) {
        int row = bm + ty * 4 + i;
        if (row < M) {
            float4 v = make_float4(acc[i][0], acc[i][1], acc[i][2], acc[i][3]);
            *(float4*)&C[row * Nn + bn + tx * 4] = v;
        }
    }
}

// ---------------------------------------------------------------- scores
// s_sc[n,h] = sum_c h[n,h,c]*a_src[h,c];  d_sc likewise. Wave per node.
template <int HC>
__global__ __launch_bounds__(256) void scores_kernel(const float* __restrict__ h,
                                                     const float* __restrict__ a_src,
                                                     const float* __restrict__ a_dst,
                                                     float* __restrict__ s_sc,
                                                     float* __restrict__ d_sc) {
    constexpr int H = HC / 64;
    int w = threadIdx.x >> 6, lane = threadIdx.x & 63;
    int n = blockIdx.x * 4 + w;
    if (n >= NNODES) return;
    bool active = (lane * 4) < HC;
    float ps = 0.f, pd = 0.f;
    if (active) {
        float4 h4  = *(const float4*)&h[n * HC + lane * 4];
        float4 as4 = *(const float4*)&a_src[lane * 4];
        float4 ad4 = *(const float4*)&a_dst[lane * 4];
        ps = h4.x * as4.x + h4.y * as4.y + h4.z * as4.z + h4.w * as4.w;
        pd = h4.x * ad4.x + h4.y * ad4.y + h4.z * ad4.z + h4.w * ad4.w;
    }
    for (int off = 8; off >= 1; off >>= 1) {
        ps += __shfl_xor(ps, off);
        pd += __shfl_xor(pd, off);
    }
    if (active && (lane & 15) == 0) {
        int hi = lane >> 4;
        s_sc[n * H + hi] = ps;
        d_sc[n * H + hi] = pd;
    }
}

// ---------------------------------------------------------------- GAT aggregate
// Wave per node: softmax over incoming edges + weighted feature sum + bias + ELU.
template <int H, int C>
__global__ __launch_bounds__(256) void agg_kernel(const float* __restrict__ hbuf,
                                                  const int* __restrict__ row_ptr,
                                                  const int* __restrict__ csr_src,
                                                  const float* __restrict__ s_sc,
                                                  const float* __restrict__ d_sc,
                                                  const float* __restrict__ bias,
                                                  float* __restrict__ out) {
    constexpr int HC = H * C;
    int w = threadIdx.x >> 6, lane = threadIdx.x & 63;
    int n = blockIdx.x * 4 + w;
    if (n >= NNODES) return;
    int r0 = row_ptr[n], deg = row_ptr[n + 1] - r0;

    float dsc[H];
#pragma unroll
    for (int h = 0; h < H; h++) dsc[h] = d_sc[n * H + h];

    // pass 1: exact segment max (lane-parallel over edges)
    float mx[H];
#pragma unroll
    for (int h = 0; h < H; h++) mx[h] = -INFINITY;
    for (int i = lane; i < deg; i += 64) {
        int s = csr_src[r0 + i];
#pragma unroll
        for (int h = 0; h < H; h++) {
            float e = s_sc[s * H + h] + dsc[h];
            e = (e >= 0.f) ? e : 0.2f * e;
            mx[h] = fmaxf(mx[h], e);
        }
    }
    for (int off = 32; off >= 1; off >>= 1)
#pragma unroll
        for (int h = 0; h < H; h++) mx[h] = fmaxf(mx[h], __shfl_xor(mx[h], off));

    // pass 2: exp/denom/feature accumulate, 64-edge chunks
    int  myh  = (lane * 4) / C;
    bool fact = (lane * 4) < HC;
    float acc[4] = {0.f, 0.f, 0.f, 0.f};
    float denom = 0.f;
    for (int base = 0; base < deg; base += 64) {
        int cnt = min(64, deg - base);
        int s_local = 0;
        float exl[H];
#pragma unroll
        for (int h = 0; h < H; h++) exl[h] = 0.f;
        if (lane < cnt) {
            s_local = csr_src[r0 + base + lane];
#pragma unroll
            for (int h = 0; h < H; h++) {
                float e = s_sc[s_local * H + h] + dsc[h];
                e = (e >= 0.f) ? e : 0.2f * e;
                exl[h] = expf(e - mx[h]);
            }
        }
        for (int j = 0; j < cnt; j++) {
            int sj = __shfl(s_local, j);
            float exj;
            if constexpr (H == 4) {
                float e0 = __shfl(exl[0], j), e1 = __shfl(exl[1], j);
                float e2 = __shfl(exl[2], j), e3 = __shfl(exl[3], j);
                exj = (myh == 0) ? e0 : (myh == 1) ? e1 : (myh == 2) ? e2 : e3;
            } else {
                exj = __shfl(exl[0], j);
            }
            denom += exj;
            if (fact) {
                float4 hv = *(const float4*)&hbuf[sj * HC + lane * 4];
                acc[0] += exj * hv.x; acc[1] += exj * hv.y;
                acc[2] += exj * hv.z; acc[3] += exj * hv.w;
            }
        }
    }
    if (fact) {
        float inv = 1.0f / (denom + 1e-16f);
#pragma unroll
        for (int k = 0; k < 4; k++) {
            float v = acc[k] * inv + bias[lane * 4 + k];
            v = (v > 0.f) ? v : expm1f(v);   // ELU
            out[n * HC + lane * 4 + k] = v;
        }
    }
}

// ---------------------------------------------------------------- batch pool
__global__ __launch_bounds__(256) void pool_kernel(const float* __restrict__ x,
                                                   const int* __restrict__ batch,
                                                   float* __restrict__ pooled,
                                                   float* __restrict__ cntb) {
    int idx = blockIdx.x * 256 + threadIdx.x;
    int n = idx >> 6, c = idx & 63;
    if (n >= NNODES) return;
    int b = batch[n];
    atomicAdd(&pooled[b * 64 + c], x[n * 64 + c]);
    if (c == 0) atomicAdd(&cntb[b], 1.0f);
}

// ---------------------------------------------------------------- MLP heads
__global__ __launch_bounds__(256) void head_kernel(const float* __restrict__ pL,
                                                   const float* __restrict__ cL,
                                                   const float* __restrict__ pR,
                                                   const float* __restrict__ cR,
                                                   const float* __restrict__ w1a,
                                                   const float* __restrict__ b1a,
                                                   const float* __restrict__ w2a,
                                                   const float* __restrict__ b2a,
                                                   const float* __restrict__ w1b,
                                                   const float* __restrict__ b1b,
                                                   const float* __restrict__ w2b,
                                                   const float* __restrict__ b2b,
                                                   float* __restrict__ out) {
    __shared__ float emb[64][128];
    __shared__ float h1[64][64];
    int t = threadIdx.x;
    for (int i = t; i < 64 * 64; i += 256) {
        int b = i >> 6, c = i & 63;
        emb[b][c]      = pL[i] / fmaxf(cL[b], 1.0f);
        emb[b][64 + c] = pR[i] / fmaxf(cR[b], 1.0f);
    }
    __syncthreads();
    // fc1 hidden
    for (int i = t; i < 4096; i += 256) {
        int b = i >> 6, c = i & 63;
        float a = b1a[c];
        for (int k = 0; k < 128; k++) a += emb[b][k] * w1a[k * 64 + c];
        h1[b][c] = fmaxf(a, 0.f);
    }
    __syncthreads();
    if (t < 128) {
        int b = t >> 1, o = t & 1;
        float a = b2a[o];
        for (int c = 0; c < 64; c++) a += h1[b][c] * w2a[c * 2 + o];
        out[b * 2 + o] = a;
    }
    __syncthreads();
    // fc2 hidden (reuse h1)
    for (int i = t; i < 4096; i += 256) {
        int b = i >> 6, c = i & 63;
        float a = b1b[c];
        for (int k = 0; k < 128; k++) a += emb[b][k] * w1b[k * 64 + c];
        h1[b][c] = fmaxf(a, 0.f);
    }
    __syncthreads();
    if (t < 128) {
        int b = t >> 1, o = t & 1;
        float a = b2b[o];
        for (int c = 0; c < 64; c++) a += h1[b][c] * w2b[c * 2 + o];
        out[128 + b * 2 + o] = a;
    }
}

// ---------------------------------------------------------------- launcher
extern "C" void kernel_launch(void* const* d_in, const int* in_sizes, int n_in,
                              void* d_out, int out_size, void* d_ws, size_t ws_size,
                              hipStream_t stream) {
    const float* x_left   = (const float*)d_in[0];
    const float* x_right  = (const float*)d_in[1];
    const int*   ei_left  = (const int*)d_in[2];
    const int*   ei_right = (const int*)d_in[3];
    const int*   ba_left  = (const int*)d_in[4];
    const int*   ba_right = (const int*)d_in[5];
    const float* w1  = (const float*)d_in[6];
    const float* as1 = (const float*)d_in[7];
    const float* ad1 = (const float*)d_in[8];
    const float* b1  = (const float*)d_in[9];
    const float* w2  = (const float*)d_in[10];
    const float* as2 = (const float*)d_in[11];
    const float* ad2 = (const float*)d_in[12];
    const float* b2  = (const float*)d_in[13];
    const float* w3  = (const float*)d_in[14];
    const float* as3 = (const float*)d_in[15];
    const float* ad3 = (const float*)d_in[16];
    const float* b3  = (const float*)d_in[17];
    const float* f1w1 = (const float*)d_in[18];
    const float* f1b1 = (const float*)d_in[19];
    const float* f1w2 = (const float*)d_in[20];
    const float* f1b2 = (const float*)d_in[21];
    const float* f2w1 = (const float*)d_in[22];
    const float* f2b1 = (const float*)d_in[23];
    const float* f2w2 = (const float*)d_in[24];
    const float* f2b2 = (const float*)d_in[25];

    // workspace carve (256B aligned)
    char* w = (char*)d_ws;
    auto carve = [&](size_t bytes) {
        void* p = (void*)w;
        w += (bytes + 255) & ~(size_t)255;
        return p;
    };
    float* buf0    = (float*)carve((size_t)NNODES * 256 * 4);
    float* buf1    = (float*)carve((size_t)NNODES * 256 * 4);
    float* s_sc    = (float*)carve((size_t)NNODES * 4 * 4);
    float* d_sc    = (float*)carve((size_t)NNODES * 4 * 4);
    int*   cnt     = (int*)carve((size_t)NNODES * 4);
    int*   row_ptr = (int*)carve((size_t)(NNODES + 1) * 4);
    int*   fillp   = (int*)carve((size_t)NNODES * 4);
    int*   csr     = (int*)carve((size_t)EPRIME * 4);
    float* pooledL = (float*)carve(64 * 64 * 4);
    float* pooledR = (float*)carve(64 * 64 * 4);
    float* cntbL   = (float*)carve(64 * 4);
    float* cntbR   = (float*)carve(64 * 4);

    const int egrid = (EPRIME + 255) / 256;
    const int ngrid = (NNODES + 3) / 4;       // wave-per-node kernels
    const int mgrid = (NNODES + 63) / 64;     // gemm row tiles

    for (int side = 0; side < 2; side++) {
        const float* x_in  = side ? x_right  : x_left;
        const int*   ei    = side ? ei_right : ei_left;
        const int*   batch = side ? ba_right : ba_left;
        float* pooled = side ? pooledR : pooledL;
        float* cntb   = side ? cntbR   : cntbL;

        // CSR by dst (shared across the 3 layers)
        hipMemsetAsync(cnt, 0, (size_t)NNODES * 4, stream);
        count_kernel<<<egrid, 256, 0, stream>>>(ei, cnt);
        scan_kernel<<<1, 256, 0, stream>>>(cnt, row_ptr, fillp);
        fill_kernel<<<egrid, 256, 0, stream>>>(ei, fillp, csr);

        // layer 1: x[N,128] @ w1[128,256]
        gemm_kernel<<<dim3(mgrid, 4), 256, 0, stream>>>(x_in, w1, buf0, NNODES, 128, 256);
        scores_kernel<256><<<ngrid, 256, 0, stream>>>(buf0, as1, ad1, s_sc, d_sc);
        agg_kernel<4, 64><<<ngrid, 256, 0, stream>>>(buf0, row_ptr, csr, s_sc, d_sc, b1, buf1);

        // layer 2: buf1[N,256] @ w2[256,256]
        gemm_kernel<<<dim3(mgrid, 4), 256, 0, stream>>>(buf1, w2, buf0, NNODES, 256, 256);
        scores_kernel<256><<<ngrid, 256, 0, stream>>>(buf0, as2, ad2, s_sc, d_sc);
        agg_kernel<4, 64><<<ngrid, 256, 0, stream>>>(buf0, row_ptr, csr, s_sc, d_sc, b2, buf1);

        // layer 3: buf1[N,256] @ w3[256,64], single head
        gemm_kernel<<<dim3(mgrid, 1), 256, 0, stream>>>(buf1, w3, buf0, NNODES, 256, 64);
        scores_kernel<64><<<ngrid, 256, 0, stream>>>(buf0, as3, ad3, s_sc, d_sc);
        agg_kernel<1, 64><<<ngrid, 256, 0, stream>>>(buf0, row_ptr, csr, s_sc, d_sc, b3, buf1);

        // batch mean-pool
        hipMemsetAsync(pooled, 0, 64 * 64 * 4, stream);
        hipMemsetAsync(cntb, 0, 64 * 4, stream);
        pool_kernel<<<(NNODES * 64 + 255) / 256, 256, 0, stream>>>(buf1, batch, pooled, cntb);
    }

    head_kernel<<<1, 256, 0, stream>>>(pooledL, cntbL, pooledR, cntbR,
                                       f1w1, f1b1, f1w2, f1b2,
                                       f2w1, f2b1, f2w2, f2b2,
                                       (float*)d_out);
}

// Round 2
// 943.865 us; speedup vs baseline: 1.2833x; 1.2833x over previous
//
#include <hip/hip_runtime.h>
#include <cstdint>
#include <cstddef>

#define NNODES 20000
#define NEDGES 320000
#define NBATCH 64
#define EPRIME (NEDGES + NNODES)

// ---------------------------------------------------------------- CSR build
__global__ __launch_bounds__(256) void count_kernel(const int* __restrict__ ei,
                                                    int* __restrict__ cnt) {
    int k = blockIdx.x * 256 + threadIdx.x;
    if (k >= EPRIME) return;
    int dst = (k < NEDGES) ? ei[NEDGES + k] : (k - NEDGES);
    atomicAdd(&cnt[dst], 1);
}

__global__ __launch_bounds__(256) void scan_kernel(const int* __restrict__ cnt,
                                                   int* __restrict__ row_ptr,
                                                   int* __restrict__ fillp) {
    __shared__ int buf[256];
    __shared__ int carry;
    int t = threadIdx.x;
    if (t == 0) carry = 0;
    __syncthreads();
    for (int base = 0; base < NNODES; base += 256) {
        int v = (base + t < NNODES) ? cnt[base + t] : 0;
        buf[t] = v;
        __syncthreads();
        for (int off = 1; off < 256; off <<= 1) {
            int add = (t >= off) ? buf[t - off] : 0;
            __syncthreads();
            buf[t] += add;
            __syncthreads();
        }
        int excl = buf[t] - v;
        if (base + t < NNODES) {
            int rp = carry + excl;
            row_ptr[base + t] = rp;
            fillp[base + t] = rp;
        }
        __syncthreads();
        if (t == 255) carry += buf[255];
        __syncthreads();
    }
    if (t == 0) row_ptr[NNODES] = carry;
}

__global__ __launch_bounds__(256) void fill_kernel(const int* __restrict__ ei,
                                                   int* __restrict__ fillp,
                                                   int* __restrict__ csr_src) {
    int k = blockIdx.x * 256 + threadIdx.x;
    if (k >= EPRIME) return;
    int src, dst;
    if (k < NEDGES) { src = ei[k]; dst = ei[NEDGES + k]; }
    else            { src = k - NEDGES; dst = src; }
    int pos = atomicAdd(&fillp[dst], 1);
    csr_src[pos] = src;
}

// ---------------------------------------------------------------- fp32 GEMM
// C[M,Nn] = A[M,K] @ B[K,Nn].  64x64 tile, BK=32, 256 threads, 4x4/thread.
__global__ __launch_bounds__(256) void gemm_kernel(const float* __restrict__ A,
                                                   const float* __restrict__ B,
                                                   float* __restrict__ C,
                                                   int M, int K, int Nn) {
    __shared__ float As[32][65];   // transposed, +1 pad kills store conflicts
    __shared__ float Bs[32][64];
    int t  = threadIdx.x;
    int bm = blockIdx.x * 64;
    int bn = blockIdx.y * 64;
    int tx = t % 16, ty = t / 16;
    float acc[4][4] = {};
    int am0 = t / 8;            // 0..31
    int ak0 = (t % 8) * 4;      // 0..28 step 4
    int bk0 = t / 16;           // 0..15
    int bn0 = (t % 16) * 4;

    for (int k0 = 0; k0 < K; k0 += 32) {
        float4 a0 = make_float4(0.f, 0.f, 0.f, 0.f);
        float4 a1 = make_float4(0.f, 0.f, 0.f, 0.f);
        int r0 = bm + am0, r1 = bm + am0 + 32;
        if (r0 < M) a0 = *(const float4*)&A[r0 * K + k0 + ak0];
        if (r1 < M) a1 = *(const float4*)&A[r1 * K + k0 + ak0];
        float4 b0  = *(const float4*)&B[(k0 + bk0) * Nn + bn + bn0];
        float4 b1v = *(const float4*)&B[(k0 + bk0 + 16) * Nn + bn + bn0];
        __syncthreads();
        As[ak0 + 0][am0] = a0.x; As[ak0 + 1][am0] = a0.y;
        As[ak0 + 2][am0] = a0.z; As[ak0 + 3][am0] = a0.w;
        As[ak0 + 0][am0 + 32] = a1.x; As[ak0 + 1][am0 + 32] = a1.y;
        As[ak0 + 2][am0 + 32] = a1.z; As[ak0 + 3][am0 + 32] = a1.w;
        *(float4*)&Bs[bk0][bn0]      = b0;
        *(float4*)&Bs[bk0 + 16][bn0] = b1v;
        __syncthreads();
#pragma unroll
        for (int kk = 0; kk < 32; kk++) {
            float4 av = *(float4*)&As[kk][ty * 4];
            float4 bv = *(float4*)&Bs[kk][tx * 4];
            acc[0][0] += av.x * bv.x; acc[0][1] += av.x * bv.y;
            acc[0][2] += av.x * bv.z; acc[0][3] += av.x * bv.w;
            acc[1][0] += av.y * bv.x; acc[1][1] += av.y * bv.y;
            acc[1][2] += av.y * bv.z; acc[1][3] += av.y * bv.w;
            acc[2][0] += av.z * bv.x; acc[2][1] += av.z * bv.y;
            acc[2][2] += av.z * bv.z; acc[2][3] += av.z * bv.w;
            acc[3][0] += av.w * bv.x; acc[3][1] += av.w * bv.y;
            acc[3][2] += av.w * bv.z; acc[3][3] += av.w * bv.w;
        }
    }
#pragma unroll
    for (int i = 0; i < 4; i++) {
        int row = bm + ty * 4 + i;
        if (row < M) {
            float4 v = make_float4(acc[i][0], acc[i][1], acc[i][2], acc[i][3]);
            *(float4*)&C[row * Nn + bn + tx * 4] = v;
        }
    }
}

// ---------------------------------------------------------------- scores
// s_sc[n,h] = sum_c h[n,h,c]*a_src[h,c];  d_sc likewise. Wave per node.
template <int HC>
__global__ __launch_bounds__(256) void scores_kernel(const float* __restrict__ h,
                                                     const float* __restrict__ a_src,
                                                     const float* __restrict__ a_dst,
                                                     float* __restrict__ s_sc,
                                                     float* __restrict__ d_sc) {
    constexpr int H = HC / 64;
    int w = threadIdx.x >> 6, lane = threadIdx.x & 63;
    int n = blockIdx.x * 4 + w;
    if (n >= NNODES) return;
    bool active = (lane * 4) < HC;
    float ps = 0.f, pd = 0.f;
    if (active) {
        float4 h4  = *(const float4*)&h[n * HC + lane * 4];
        float4 as4 = *(const float4*)&a_src[lane * 4];
        float4 ad4 = *(const float4*)&a_dst[lane * 4];
        ps = h4.x * as4.x + h4.y * as4.y + h4.z * as4.z + h4.w * as4.w;
        pd = h4.x * ad4.x + h4.y * ad4.y + h4.z * ad4.z + h4.w * ad4.w;
    }
    for (int off = 8; off >= 1; off >>= 1) {
        ps += __shfl_xor(ps, off);
        pd += __shfl_xor(pd, off);
    }
    if (active && (lane & 15) == 0) {
        int hi = lane >> 4;
        s_sc[n * H + hi] = ps;
        d_sc[n * H + hi] = pd;
    }
}

// ---------------------------------------------------------------- GAT aggregate
// Wave per node: softmax over incoming edges + weighted feature sum + bias + ELU.
template <int H, int C>
__global__ __launch_bounds__(256) void agg_kernel(const float* __restrict__ hbuf,
                                                  const int* __restrict__ row_ptr,
                                                  const int* __restrict__ csr_src,
                                                  const float* __restrict__ s_sc,
                                                  const float* __restrict__ d_sc,
                                                  const float* __restrict__ bias,
                                                  float* __restrict__ out) {
    constexpr int HC = H * C;
    int w = threadIdx.x >> 6, lane = threadIdx.x & 63;
    int n = blockIdx.x * 4 + w;
    if (n >= NNODES) return;
    int r0 = row_ptr[n], deg = row_ptr[n + 1] - r0;

    float dsc[H];
#pragma unroll
    for (int h = 0; h < H; h++) dsc[h] = d_sc[n * H + h];

    // pass 1: exact segment max (lane-parallel over edges)
    float mx[H];
#pragma unroll
    for (int h = 0; h < H; h++) mx[h] = -INFINITY;
    for (int i = lane; i < deg; i += 64) {
        int s = csr_src[r0 + i];
#pragma unroll
        for (int h = 0; h < H; h++) {
            float e = s_sc[s * H + h] + dsc[h];
            e = (e >= 0.f) ? e : 0.2f * e;
            mx[h] = fmaxf(mx[h], e);
        }
    }
    for (int off = 32; off >= 1; off >>= 1)
#pragma unroll
        for (int h = 0; h < H; h++) mx[h] = fmaxf(mx[h], __shfl_xor(mx[h], off));

    // pass 2: exp/denom/feature accumulate, 64-edge chunks
    int  myh  = (lane * 4) / C;
    bool fact = (lane * 4) < HC;
    float acc[4] = {0.f, 0.f, 0.f, 0.f};
    float denom = 0.f;
    for (int base = 0; base < deg; base += 64) {
        int cnt = min(64, deg - base);
        int s_local = 0;
        float exl[H];
#pragma unroll
        for (int h = 0; h < H; h++) exl[h] = 0.f;
        if (lane < cnt) {
            s_local = csr_src[r0 + base + lane];
#pragma unroll
            for (int h = 0; h < H; h++) {
                float e = s_sc[s_local * H + h] + dsc[h];
                e = (e >= 0.f) ? e : 0.2f * e;
                exl[h] = expf(e - mx[h]);
            }
        }
        for (int j = 0; j < cnt; j++) {
            int sj = __shfl(s_local, j);
            float exj;
            if constexpr (H == 4) {
                float e0 = __shfl(exl[0], j), e1 = __shfl(exl[1], j);
                float e2 = __shfl(exl[2], j), e3 = __shfl(exl[3], j);
                exj = (myh == 0) ? e0 : (myh == 1) ? e1 : (myh == 2) ? e2 : e3;
            } else {
                exj = __shfl(exl[0], j);
            }
            denom += exj;
            if (fact) {
                float4 hv = *(const float4*)&hbuf[sj * HC + lane * 4];
                acc[0] += exj * hv.x; acc[1] += exj * hv.y;
                acc[2] += exj * hv.z; acc[3] += exj * hv.w;
            }
        }
    }
    if (fact) {
        float inv = 1.0f / (denom + 1e-16f);
#pragma unroll
        for (int k = 0; k < 4; k++) {
            float v = acc[k] * inv + bias[lane * 4 + k];
            v = (v > 0.f) ? v : expm1f(v);   // ELU
            out[n * HC + lane * 4 + k] = v;
        }
    }
}

// ---------------------------------------------------------------- batch pool
// batch[] is SORTED: one block per batch slot, binary-search the node range,
// direct sum (no atomics), LDS-reduce 4 wave partials.
__global__ __launch_bounds__(256) void pool_kernel(const float* __restrict__ x,
                                                   const int* __restrict__ batch,
                                                   float* __restrict__ pooled,
                                                   float* __restrict__ cntb) {
    int b = blockIdx.x;
    // lower_bound(batch, b) and lower_bound(batch, b+1), redundantly per thread
    int lo = 0, hi = NNODES;
    while (lo < hi) { int mid = (lo + hi) >> 1; if (batch[mid] < b) lo = mid + 1; else hi = mid; }
    int start = lo;
    hi = NNODES;
    while (lo < hi) { int mid = (lo + hi) >> 1; if (batch[mid] < b + 1) lo = mid + 1; else hi = mid; }
    int end = lo;

    int t = threadIdx.x;
    int c = t & 63, g = t >> 6;          // channel, node-stride group (4)
    float s = 0.f;
    for (int n = start + g; n < end; n += 4) s += x[n * 64 + c];
    __shared__ float buf[4][64];
    buf[g][c] = s;
    __syncthreads();
    if (t < 64) {
        pooled[b * 64 + t] = buf[0][t] + buf[1][t] + buf[2][t] + buf[3][t];
        if (t == 0) cntb[b] = (float)(end - start);
    }
}

// ---------------------------------------------------------------- MLP heads
__global__ __launch_bounds__(256) void head_kernel(const float* __restrict__ pL,
                                                   const float* __restrict__ cL,
                                                   const float* __restrict__ pR,
                                                   const float* __restrict__ cR,
                                                   const float* __restrict__ w1a,
                                                   const float* __restrict__ b1a,
                                                   const float* __restrict__ w2a,
                                                   const float* __restrict__ b2a,
                                                   const float* __restrict__ w1b,
                                                   const float* __restrict__ b1b,
                                                   const float* __restrict__ w2b,
                                                   const float* __restrict__ b2b,
                                                   float* __restrict__ out) {
    __shared__ float emb[64][128];
    __shared__ float h1[64][64];
    int t = threadIdx.x;
    for (int i = t; i < 64 * 64; i += 256) {
        int b = i >> 6, c = i & 63;
        emb[b][c]      = pL[i] / fmaxf(cL[b], 1.0f);
        emb[b][64 + c] = pR[i] / fmaxf(cR[b], 1.0f);
    }
    __syncthreads();
    // fc1 hidden
    for (int i = t; i < 4096; i += 256) {
        int b = i >> 6, c = i & 63;
        float a = b1a[c];
        for (int k = 0; k < 128; k++) a += emb[b][k] * w1a[k * 64 + c];
        h1[b][c] = fmaxf(a, 0.f);
    }
    __syncthreads();
    if (t < 128) {
        int b = t >> 1, o = t & 1;
        float a = b2a[o];
        for (int c = 0; c < 64; c++) a += h1[b][c] * w2a[c * 2 + o];
        out[b * 2 + o] = a;
    }
    __syncthreads();
    // fc2 hidden (reuse h1)
    for (int i = t; i < 4096; i += 256) {
        int b = i >> 6, c = i & 63;
        float a = b1b[c];
        for (int k = 0; k < 128; k++) a += emb[b][k] * w1b[k * 64 + c];
        h1[b][c] = fmaxf(a, 0.f);
    }
    __syncthreads();
    if (t < 128) {
        int b = t >> 1, o = t & 1;
        float a = b2b[o];
        for (int c = 0; c < 64; c++) a += h1[b][c] * w2b[c * 2 + o];
        out[128 + b * 2 + o] = a;
    }
}

// ---------------------------------------------------------------- launcher
extern "C" void kernel_launch(void* const* d_in, const int* in_sizes, int n_in,
                              void* d_out, int out_size, void* d_ws, size_t ws_size,
                              hipStream_t stream) {
    const float* x_left   = (const float*)d_in[0];
    const float* x_right  = (const float*)d_in[1];
    const int*   ei_left  = (const int*)d_in[2];
    const int*   ei_right = (const int*)d_in[3];
    const int*   ba_left  = (const int*)d_in[4];
    const int*   ba_right = (const int*)d_in[5];
    const float* w1  = (const float*)d_in[6];
    const float* as1 = (const float*)d_in[7];
    const float* ad1 = (const float*)d_in[8];
    const float* b1  = (const float*)d_in[9];
    const float* w2  = (const float*)d_in[10];
    const float* as2 = (const float*)d_in[11];
    const float* ad2 = (const float*)d_in[12];
    const float* b2  = (const float*)d_in[13];
    const float* w3  = (const float*)d_in[14];
    const float* as3 = (const float*)d_in[15];
    const float* ad3 = (const float*)d_in[16];
    const float* b3  = (const float*)d_in[17];
    const float* f1w1 = (const float*)d_in[18];
    const float* f1b1 = (const float*)d_in[19];
    const float* f1w2 = (const float*)d_in[20];
    const float* f1b2 = (const float*)d_in[21];
    const float* f2w1 = (const float*)d_in[22];
    const float* f2b1 = (const float*)d_in[23];
    const float* f2w2 = (const float*)d_in[24];
    const float* f2b2 = (const float*)d_in[25];

    // workspace carve (256B aligned)
    char* w = (char*)d_ws;
    auto carve = [&](size_t bytes) {
        void* p = (void*)w;
        w += (bytes + 255) & ~(size_t)255;
        return p;
    };
    float* buf0    = (float*)carve((size_t)NNODES * 256 * 4);
    float* buf1    = (float*)carve((size_t)NNODES * 256 * 4);
    float* s_sc    = (float*)carve((size_t)NNODES * 4 * 4);
    float* d_sc    = (float*)carve((size_t)NNODES * 4 * 4);
    int*   cnt     = (int*)carve((size_t)NNODES * 4);
    int*   row_ptr = (int*)carve((size_t)(NNODES + 1) * 4);
    int*   fillp   = (int*)carve((size_t)NNODES * 4);
    int*   csr     = (int*)carve((size_t)EPRIME * 4);
    float* pooledL = (float*)carve(64 * 64 * 4);
    float* pooledR = (float*)carve(64 * 64 * 4);
    float* cntbL   = (float*)carve(64 * 4);
    float* cntbR   = (float*)carve(64 * 4);

    const int egrid = (EPRIME + 255) / 256;
    const int ngrid = (NNODES + 3) / 4;       // wave-per-node kernels
    const int mgrid = (NNODES + 63) / 64;     // gemm row tiles

    for (int side = 0; side < 2; side++) {
        const float* x_in  = side ? x_right  : x_left;
        const int*   ei    = side ? ei_right : ei_left;
        const int*   batch = side ? ba_right : ba_left;
        float* pooled = side ? pooledR : pooledL;
        float* cntb   = side ? cntbR   : cntbL;

        // CSR by dst (shared across the 3 layers)
        hipMemsetAsync(cnt, 0, (size_t)NNODES * 4, stream);
        count_kernel<<<egrid, 256, 0, stream>>>(ei, cnt);
        scan_kernel<<<1, 256, 0, stream>>>(cnt, row_ptr, fillp);
        fill_kernel<<<egrid, 256, 0, stream>>>(ei, fillp, csr);

        // layer 1: x[N,128] @ w1[128,256]
        gemm_kernel<<<dim3(mgrid, 4), 256, 0, stream>>>(x_in, w1, buf0, NNODES, 128, 256);
        scores_kernel<256><<<ngrid, 256, 0, stream>>>(buf0, as1, ad1, s_sc, d_sc);
        agg_kernel<4, 64><<<ngrid, 256, 0, stream>>>(buf0, row_ptr, csr, s_sc, d_sc, b1, buf1);

        // layer 2: buf1[N,256] @ w2[256,256]
        gemm_kernel<<<dim3(mgrid, 4), 256, 0, stream>>>(buf1, w2, buf0, NNODES, 256, 256);
        scores_kernel<256><<<ngrid, 256, 0, stream>>>(buf0, as2, ad2, s_sc, d_sc);
        agg_kernel<4, 64><<<ngrid, 256, 0, stream>>>(buf0, row_ptr, csr, s_sc, d_sc, b2, buf1);

        // layer 3: buf1[N,256] @ w3[256,64], single head
        gemm_kernel<<<dim3(mgrid, 1), 256, 0, stream>>>(buf1, w3, buf0, NNODES, 256, 64);
        scores_kernel<64><<<ngrid, 256, 0, stream>>>(buf0, as3, ad3, s_sc, d_sc);
        agg_kernel<1, 64><<<ngrid, 256, 0, stream>>>(buf0, row_ptr, csr, s_sc, d_sc, b3, buf1);

        // batch mean-pool: one block per batch slot, no atomics (batch sorted)
        pool_kernel<<<NBATCH, 256, 0, stream>>>(buf1, batch, pooled, cntb);
    }

    head_kernel<<<1, 256, 0, stream>>>(pooledL, cntbL, pooledR, cntbR,
                                       f1w1, f1b1, f1w2, f1b2,
                                       f2w1, f2b1, f2w2, f2b2,
                                       (float*)d_out);
}

// Round 3
// 817.636 us; speedup vs baseline: 1.4814x; 1.1544x over previous
//
#include <hip/hip_runtime.h>
#include <cstdint>
#include <cstddef>

#define NNODES 20000
#define NEDGES 320000
#define NBATCH 64
#define EPRIME (NEDGES + NNODES)

// ---------------------------------------------------------------- CSR build
__global__ __launch_bounds__(256) void count_kernel(const int* __restrict__ ei,
                                                    int* __restrict__ cnt) {
    int k = blockIdx.x * 256 + threadIdx.x;
    if (k >= EPRIME) return;
    int dst = (k < NEDGES) ? ei[NEDGES + k] : (k - NEDGES);
    atomicAdd(&cnt[dst], 1);
}

// Register-blocked exclusive scan: 1 block x 1024 threads x 20 elems/thread.
// 2 barriers total (vs ~1300 in the naive version).
__global__ __launch_bounds__(1024) void scan_kernel(const int* __restrict__ cnt,
                                                    int* __restrict__ row_ptr,
                                                    int* __restrict__ fillp) {
    constexpr int CHUNK = 20;              // 1024*20 = 20480 >= NNODES
    int t = threadIdx.x;
    int base = t * CHUNK;
    int v[CHUNK];
    int sum = 0;
#pragma unroll
    for (int i = 0; i < CHUNK; i++) {
        int idx = base + i;
        v[i] = (idx < NNODES) ? cnt[idx] : 0;
        sum += v[i];
    }
    int lane = t & 63, wid = t >> 6;       // 16 waves
    int s = sum;
    for (int off = 1; off < 64; off <<= 1) {
        int x = __shfl_up(s, off);
        if (lane >= off) s += x;
    }
    __shared__ int wsum[16];
    __shared__ int woff[17];
    if (lane == 63) wsum[wid] = s;
    __syncthreads();
    if (t == 0) {
        int acc = 0;
        for (int i = 0; i < 16; i++) { woff[i] = acc; acc += wsum[i]; }
        woff[16] = acc;
    }
    __syncthreads();
    int excl = woff[wid] + s - sum;        // exclusive prefix at chunk start
#pragma unroll
    for (int i = 0; i < CHUNK; i++) {
        int idx = base + i;
        if (idx < NNODES) { row_ptr[idx] = excl; fillp[idx] = excl; }
        excl += v[i];
    }
    if (t == 0) row_ptr[NNODES] = woff[16];
}

__global__ __launch_bounds__(256) void fill_kernel(const int* __restrict__ ei,
                                                   int* __restrict__ fillp,
                                                   int* __restrict__ csr_src) {
    int k = blockIdx.x * 256 + threadIdx.x;
    if (k >= EPRIME) return;
    int src, dst;
    if (k < NEDGES) { src = ei[k]; dst = ei[NEDGES + k]; }
    else            { src = k - NEDGES; dst = src; }
    int pos = atomicAdd(&fillp[dst], 1);
    csr_src[pos] = src;
}

// ---------------------------------------------------------------- fp32 GEMM
// C[M,Nn] = A[M,K] @ B[K,Nn].  64x64 tile, BK=32, 256 threads, 4x4/thread.
__global__ __launch_bounds__(256) void gemm_kernel(const float* __restrict__ A,
                                                   const float* __restrict__ B,
                                                   float* __restrict__ C,
                                                   int M, int K, int Nn) {
    __shared__ float As[32][65];   // transposed, +1 pad kills store conflicts
    __shared__ float Bs[32][64];
    int t  = threadIdx.x;
    int bm = blockIdx.x * 64;
    int bn = blockIdx.y * 64;
    int tx = t % 16, ty = t / 16;
    float acc[4][4] = {};
    int am0 = t / 8;            // 0..31
    int ak0 = (t % 8) * 4;      // 0..28 step 4
    int bk0 = t / 16;           // 0..15
    int bn0 = (t % 16) * 4;

    for (int k0 = 0; k0 < K; k0 += 32) {
        float4 a0 = make_float4(0.f, 0.f, 0.f, 0.f);
        float4 a1 = make_float4(0.f, 0.f, 0.f, 0.f);
        int r0 = bm + am0, r1 = bm + am0 + 32;
        if (r0 < M) a0 = *(const float4*)&A[r0 * K + k0 + ak0];
        if (r1 < M) a1 = *(const float4*)&A[r1 * K + k0 + ak0];
        float4 b0  = *(const float4*)&B[(k0 + bk0) * Nn + bn + bn0];
        float4 b1v = *(const float4*)&B[(k0 + bk0 + 16) * Nn + bn + bn0];
        __syncthreads();
        As[ak0 + 0][am0] = a0.x; As[ak0 + 1][am0] = a0.y;
        As[ak0 + 2][am0] = a0.z; As[ak0 + 3][am0] = a0.w;
        As[ak0 + 0][am0 + 32] = a1.x; As[ak0 + 1][am0 + 32] = a1.y;
        As[ak0 + 2][am0 + 32] = a1.z; As[ak0 + 3][am0 + 32] = a1.w;
        *(float4*)&Bs[bk0][bn0]      = b0;
        *(float4*)&Bs[bk0 + 16][bn0] = b1v;
        __syncthreads();
#pragma unroll
        for (int kk = 0; kk < 32; kk++) {
            float4 av = *(float4*)&As[kk][ty * 4];
            float4 bv = *(float4*)&Bs[kk][tx * 4];
            acc[0][0] += av.x * bv.x; acc[0][1] += av.x * bv.y;
            acc[0][2] += av.x * bv.z; acc[0][3] += av.x * bv.w;
            acc[1][0] += av.y * bv.x; acc[1][1] += av.y * bv.y;
            acc[1][2] += av.y * bv.z; acc[1][3] += av.y * bv.w;
            acc[2][0] += av.z * bv.x; acc[2][1] += av.z * bv.y;
            acc[2][2] += av.z * bv.z; acc[2][3] += av.z * bv.w;
            acc[3][0] += av.w * bv.x; acc[3][1] += av.w * bv.y;
            acc[3][2] += av.w * bv.z; acc[3][3] += av.w * bv.w;
        }
    }
#pragma unroll
    for (int i = 0; i < 4; i++) {
        int row = bm + ty * 4 + i;
        if (row < M) {
            float4 v = make_float4(acc[i][0], acc[i][1], acc[i][2], acc[i][3]);
            *(float4*)&C[row * Nn + bn + tx * 4] = v;
        }
    }
}

// ---------------------------------------------------------------- scores
// s_sc[n,h] = sum_c h[n,h,c]*a_src[h,c];  d_sc likewise. Wave per node.
template <int HC>
__global__ __launch_bounds__(256) void scores_kernel(const float* __restrict__ h,
                                                     const float* __restrict__ a_src,
                                                     const float* __restrict__ a_dst,
                                                     float* __restrict__ s_sc,
                                                     float* __restrict__ d_sc) {
    constexpr int H = HC / 64;
    int w = threadIdx.x >> 6, lane = threadIdx.x & 63;
    int n = blockIdx.x * 4 + w;
    if (n >= NNODES) return;
    bool active = (lane * 4) < HC;
    float ps = 0.f, pd = 0.f;
    if (active) {
        float4 h4  = *(const float4*)&h[n * HC + lane * 4];
        float4 as4 = *(const float4*)&a_src[lane * 4];
        float4 ad4 = *(const float4*)&a_dst[lane * 4];
        ps = h4.x * as4.x + h4.y * as4.y + h4.z * as4.z + h4.w * as4.w;
        pd = h4.x * ad4.x + h4.y * ad4.y + h4.z * ad4.z + h4.w * ad4.w;
    }
    for (int off = 8; off >= 1; off >>= 1) {
        ps += __shfl_xor(ps, off);
        pd += __shfl_xor(pd, off);
    }
    if (active && (lane & 15) == 0) {
        int hi = lane >> 4;
        s_sc[n * H + hi] = ps;
        d_sc[n * H + hi] = pd;
    }
}

// ---------------------------------------------------------------- GAT aggregate
// Wave per node: softmax over incoming edges + weighted feature sum + bias + ELU.
template <int H, int C>
__global__ __launch_bounds__(256) void agg_kernel(const float* __restrict__ hbuf,
                                                  const int* __restrict__ row_ptr,
                                                  const int* __restrict__ csr_src,
                                                  const float* __restrict__ s_sc,
                                                  const float* __restrict__ d_sc,
                                                  const float* __restrict__ bias,
                                                  float* __restrict__ out) {
    constexpr int HC = H * C;
    int w = threadIdx.x >> 6, lane = threadIdx.x & 63;
    int n = blockIdx.x * 4 + w;
    if (n >= NNODES) return;
    int r0 = row_ptr[n], deg = row_ptr[n + 1] - r0;

    float dsc[H];
#pragma unroll
    for (int h = 0; h < H; h++) dsc[h] = d_sc[n * H + h];

    // pass 1: exact segment max (lane-parallel over edges)
    float mx[H];
#pragma unroll
    for (int h = 0; h < H; h++) mx[h] = -INFINITY;
    for (int i = lane; i < deg; i += 64) {
        int s = csr_src[r0 + i];
#pragma unroll
        for (int h = 0; h < H; h++) {
            float e = s_sc[s * H + h] + dsc[h];
            e = (e >= 0.f) ? e : 0.2f * e;
            mx[h] = fmaxf(mx[h], e);
        }
    }
    for (int off = 32; off >= 1; off >>= 1)
#pragma unroll
        for (int h = 0; h < H; h++) mx[h] = fmaxf(mx[h], __shfl_xor(mx[h], off));

    // pass 2: exp/denom/feature accumulate, 64-edge chunks
    int  myh  = (lane * 4) / C;
    bool fact = (lane * 4) < HC;
    float acc[4] = {0.f, 0.f, 0.f, 0.f};
    float denom = 0.f;
    for (int base = 0; base < deg; base += 64) {
        int cnt = min(64, deg - base);
        int s_local = 0;
        float exl[H];
#pragma unroll
        for (int h = 0; h < H; h++) exl[h] = 0.f;
        if (lane < cnt) {
            s_local = csr_src[r0 + base + lane];
#pragma unroll
            for (int h = 0; h < H; h++) {
                float e = s_sc[s_local * H + h] + dsc[h];
                e = (e >= 0.f) ? e : 0.2f * e;
                exl[h] = expf(e - mx[h]);
            }
        }
        for (int j = 0; j < cnt; j++) {
            int sj = __shfl(s_local, j);
            float exj;
            if constexpr (H == 4) {
                float e0 = __shfl(exl[0], j), e1 = __shfl(exl[1], j);
                float e2 = __shfl(exl[2], j), e3 = __shfl(exl[3], j);
                exj = (myh == 0) ? e0 : (myh == 1) ? e1 : (myh == 2) ? e2 : e3;
            } else {
                exj = __shfl(exl[0], j);
            }
            denom += exj;
            if (fact) {
                float4 hv = *(const float4*)&hbuf[sj * HC + lane * 4];
                acc[0] += exj * hv.x; acc[1] += exj * hv.y;
                acc[2] += exj * hv.z; acc[3] += exj * hv.w;
            }
        }
    }
    if (fact) {
        float inv = 1.0f / (denom + 1e-16f);
#pragma unroll
        for (int k = 0; k < 4; k++) {
            float v = acc[k] * inv + bias[lane * 4 + k];
            v = (v > 0.f) ? v : expm1f(v);   // ELU
            out[n * HC + lane * 4 + k] = v;
        }
    }
}

// ---------------------------------------------------------------- batch pool
// batch[] is SORTED: one block per batch slot, binary-search the node range,
// direct sum (no atomics), LDS-reduce 4 wave partials.
__global__ __launch_bounds__(256) void pool_kernel(const float* __restrict__ x,
                                                   const int* __restrict__ batch,
                                                   float* __restrict__ pooled,
                                                   float* __restrict__ cntb) {
    int b = blockIdx.x;
    int lo = 0, hi = NNODES;
    while (lo < hi) { int mid = (lo + hi) >> 1; if (batch[mid] < b) lo = mid + 1; else hi = mid; }
    int start = lo;
    hi = NNODES;
    while (lo < hi) { int mid = (lo + hi) >> 1; if (batch[mid] < b + 1) lo = mid + 1; else hi = mid; }
    int end = lo;

    int t = threadIdx.x;
    int c = t & 63, g = t >> 6;          // channel, node-stride group (4)
    float s = 0.f;
    for (int n = start + g; n < end; n += 4) s += x[n * 64 + c];
    __shared__ float buf[4][64];
    buf[g][c] = s;
    __syncthreads();
    if (t < 64) {
        pooled[b * 64 + t] = buf[0][t] + buf[1][t] + buf[2][t] + buf[3][t];
        if (t == 0) cntb[b] = (float)(end - start);
    }
}

// ---------------------------------------------------------------- MLP heads
__global__ __launch_bounds__(256) void head_kernel(const float* __restrict__ pL,
                                                   const float* __restrict__ cL,
                                                   const float* __restrict__ pR,
                                                   const float* __restrict__ cR,
                                                   const float* __restrict__ w1a,
                                                   const float* __restrict__ b1a,
                                                   const float* __restrict__ w2a,
                                                   const float* __restrict__ b2a,
                                                   const float* __restrict__ w1b,
                                                   const float* __restrict__ b1b,
                                                   const float* __restrict__ w2b,
                                                   const float* __restrict__ b2b,
                                                   float* __restrict__ out) {
    __shared__ float emb[64][128];
    __shared__ float h1[64][64];
    int t = threadIdx.x;
    for (int i = t; i < 64 * 64; i += 256) {
        int b = i >> 6, c = i & 63;
        emb[b][c]      = pL[i] / fmaxf(cL[b], 1.0f);
        emb[b][64 + c] = pR[i] / fmaxf(cR[b], 1.0f);
    }
    __syncthreads();
    // fc1 hidden
    for (int i = t; i < 4096; i += 256) {
        int b = i >> 6, c = i & 63;
        float a = b1a[c];
        for (int k = 0; k < 128; k++) a += emb[b][k] * w1a[k * 64 + c];
        h1[b][c] = fmaxf(a, 0.f);
    }
    __syncthreads();
    if (t < 128) {
        int b = t >> 1, o = t & 1;
        float a = b2a[o];
        for (int c = 0; c < 64; c++) a += h1[b][c] * w2a[c * 2 + o];
        out[b * 2 + o] = a;
    }
    __syncthreads();
    // fc2 hidden (reuse h1)
    for (int i = t; i < 4096; i += 256) {
        int b = i >> 6, c = i & 63;
        float a = b1b[c];
        for (int k = 0; k < 128; k++) a += emb[b][k] * w1b[k * 64 + c];
        h1[b][c] = fmaxf(a, 0.f);
    }
    __syncthreads();
    if (t < 128) {
        int b = t >> 1, o = t & 1;
        float a = b2b[o];
        for (int c = 0; c < 64; c++) a += h1[b][c] * w2b[c * 2 + o];
        out[128 + b * 2 + o] = a;
    }
}

// ---------------------------------------------------------------- launcher
extern "C" void kernel_launch(void* const* d_in, const int* in_sizes, int n_in,
                              void* d_out, int out_size, void* d_ws, size_t ws_size,
                              hipStream_t stream) {
    const float* x_left   = (const float*)d_in[0];
    const float* x_right  = (const float*)d_in[1];
    const int*   ei_left  = (const int*)d_in[2];
    const int*   ei_right = (const int*)d_in[3];
    const int*   ba_left  = (const int*)d_in[4];
    const int*   ba_right = (const int*)d_in[5];
    const float* w1  = (const float*)d_in[6];
    const float* as1 = (const float*)d_in[7];
    const float* ad1 = (const float*)d_in[8];
    const float* b1  = (const float*)d_in[9];
    const float* w2  = (const float*)d_in[10];
    const float* as2 = (const float*)d_in[11];
    const float* ad2 = (const float*)d_in[12];
    const float* b2  = (const float*)d_in[13];
    const float* w3  = (const float*)d_in[14];
    const float* as3 = (const float*)d_in[15];
    const float* ad3 = (const float*)d_in[16];
    const float* b3  = (const float*)d_in[17];
    const float* f1w1 = (const float*)d_in[18];
    const float* f1b1 = (const float*)d_in[19];
    const float* f1w2 = (const float*)d_in[20];
    const float* f1b2 = (const float*)d_in[21];
    const float* f2w1 = (const float*)d_in[22];
    const float* f2b1 = (const float*)d_in[23];
    const float* f2w2 = (const float*)d_in[24];
    const float* f2b2 = (const float*)d_in[25];

    // workspace carve (256B aligned)
    char* w = (char*)d_ws;
    auto carve = [&](size_t bytes) {
        void* p = (void*)w;
        w += (bytes + 255) & ~(size_t)255;
        return p;
    };
    float* buf0    = (float*)carve((size_t)NNODES * 256 * 4);
    float* buf1    = (float*)carve((size_t)NNODES * 256 * 4);
    float* s_sc    = (float*)carve((size_t)NNODES * 4 * 4);
    float* d_sc    = (float*)carve((size_t)NNODES * 4 * 4);
    int*   cnt     = (int*)carve((size_t)NNODES * 4);
    int*   row_ptr = (int*)carve((size_t)(NNODES + 1) * 4);
    int*   fillp   = (int*)carve((size_t)NNODES * 4);
    int*   csr     = (int*)carve((size_t)EPRIME * 4);
    float* pooledL = (float*)carve(64 * 64 * 4);
    float* pooledR = (float*)carve(64 * 64 * 4);
    float* cntbL   = (float*)carve(64 * 4);
    float* cntbR   = (float*)carve(64 * 4);

    const int egrid = (EPRIME + 255) / 256;
    const int ngrid = (NNODES + 3) / 4;       // wave-per-node kernels
    const int mgrid = (NNODES + 63) / 64;     // gemm row tiles

    for (int side = 0; side < 2; side++) {
        const float* x_in  = side ? x_right  : x_left;
        const int*   ei    = side ? ei_right : ei_left;
        const int*   batch = side ? ba_right : ba_left;
        float* pooled = side ? pooledR : pooledL;
        float* cntb   = side ? cntbR   : cntbL;

        // CSR by dst (shared across the 3 layers)
        hipMemsetAsync(cnt, 0, (size_t)NNODES * 4, stream);
        count_kernel<<<egrid, 256, 0, stream>>>(ei, cnt);
        scan_kernel<<<1, 1024, 0, stream>>>(cnt, row_ptr, fillp);
        fill_kernel<<<egrid, 256, 0, stream>>>(ei, fillp, csr);

        // layer 1: x[N,128] @ w1[128,256]
        gemm_kernel<<<dim3(mgrid, 4), 256, 0, stream>>>(x_in, w1, buf0, NNODES, 128, 256);
        scores_kernel<256><<<ngrid, 256, 0, stream>>>(buf0, as1, ad1, s_sc, d_sc);
        agg_kernel<4, 64><<<ngrid, 256, 0, stream>>>(buf0, row_ptr, csr, s_sc, d_sc, b1, buf1);

        // layer 2: buf1[N,256] @ w2[256,256]
        gemm_kernel<<<dim3(mgrid, 4), 256, 0, stream>>>(buf1, w2, buf0, NNODES, 256, 256);
        scores_kernel<256><<<ngrid, 256, 0, stream>>>(buf0, as2, ad2, s_sc, d_sc);
        agg_kernel<4, 64><<<ngrid, 256, 0, stream>>>(buf0, row_ptr, csr, s_sc, d_sc, b2, buf1);

        // layer 3: buf1[N,256] @ w3[256,64], single head
        gemm_kernel<<<dim3(mgrid, 1), 256, 0, stream>>>(buf1, w3, buf0, NNODES, 256, 64);
        scores_kernel<64><<<ngrid, 256, 0, stream>>>(buf0, as3, ad3, s_sc, d_sc);
        agg_kernel<1, 64><<<ngrid, 256, 0, stream>>>(buf0, row_ptr, csr, s_sc, d_sc, b3, buf1);

        // batch mean-pool: one block per batch slot, no atomics (batch sorted)
        pool_kernel<<<NBATCH, 256, 0, stream>>>(buf1, batch, pooled, cntb);
    }

    head_kernel<<<1, 256, 0, stream>>>(pooledL, cntbL, pooledR, cntbR,
                                       f1w1, f1b1, f1w2, f1b2,
                                       f2w1, f2b1, f2w2, f2b2,
                                       (float*)d_out);
}

// Round 4
// 770.115 us; speedup vs baseline: 1.5728x; 1.0617x over previous
//
#include <hip/hip_runtime.h>
#include <cstdint>
#include <cstddef>

#define NNODES 20000
#define NEDGES 320000
#define NBATCH 64
#define EPRIME (NEDGES + NNODES)

// ---------------------------------------------------------------- CSR build
__global__ __launch_bounds__(256) void count_kernel(const int* __restrict__ ei,
                                                    int* __restrict__ cnt) {
    int k = blockIdx.x * 256 + threadIdx.x;
    if (k >= EPRIME) return;
    int dst = (k < NEDGES) ? ei[NEDGES + k] : (k - NEDGES);
    atomicAdd(&cnt[dst], 1);
}

// Register-blocked exclusive scan: 1 block x 1024 threads x 20 elems/thread.
__global__ __launch_bounds__(1024) void scan_kernel(const int* __restrict__ cnt,
                                                    int* __restrict__ row_ptr,
                                                    int* __restrict__ fillp) {
    constexpr int CHUNK = 20;              // 1024*20 = 20480 >= NNODES
    int t = threadIdx.x;
    int base = t * CHUNK;
    int v[CHUNK];
    int sum = 0;
#pragma unroll
    for (int i = 0; i < CHUNK; i++) {
        int idx = base + i;
        v[i] = (idx < NNODES) ? cnt[idx] : 0;
        sum += v[i];
    }
    int lane = t & 63, wid = t >> 6;       // 16 waves
    int s = sum;
    for (int off = 1; off < 64; off <<= 1) {
        int x = __shfl_up(s, off);
        if (lane >= off) s += x;
    }
    __shared__ int wsum[16];
    __shared__ int woff[17];
    if (lane == 63) wsum[wid] = s;
    __syncthreads();
    if (t == 0) {
        int acc = 0;
        for (int i = 0; i < 16; i++) { woff[i] = acc; acc += wsum[i]; }
        woff[16] = acc;
    }
    __syncthreads();
    int excl = woff[wid] + s - sum;        // exclusive prefix at chunk start
#pragma unroll
    for (int i = 0; i < CHUNK; i++) {
        int idx = base + i;
        if (idx < NNODES) { row_ptr[idx] = excl; fillp[idx] = excl; }
        excl += v[i];
    }
    if (t == 0) row_ptr[NNODES] = woff[16];
}

__global__ __launch_bounds__(256) void fill_kernel(const int* __restrict__ ei,
                                                   int* __restrict__ fillp,
                                                   int* __restrict__ csr_src) {
    int k = blockIdx.x * 256 + threadIdx.x;
    if (k >= EPRIME) return;
    int src, dst;
    if (k < NEDGES) { src = ei[k]; dst = ei[NEDGES + k]; }
    else            { src = k - NEDGES; dst = src; }
    int pos = atomicAdd(&fillp[dst], 1);
    csr_src[pos] = src;
}

// ---------------------------------------------------------------- fp32 GEMM + fused scores
// C[M,Nn] = A[M,K] @ B[K,Nn].  64x64 tile, BK=32, 256 threads, 4x4/thread.
// Head width C==64 equals the N-tile width, so head index = blockIdx.y and each
// block fully computes s_sc/d_sc for its 64 rows (16-lane shuffle reduction).
__global__ __launch_bounds__(256) void gemm_kernel(const float* __restrict__ A,
                                                   const float* __restrict__ B,
                                                   float* __restrict__ C,
                                                   int M, int K, int Nn,
                                                   const float* __restrict__ a_src,
                                                   const float* __restrict__ a_dst,
                                                   float* __restrict__ s_sc,
                                                   float* __restrict__ d_sc,
                                                   int H) {
    __shared__ float As[32][65];   // transposed, +1 pad kills store conflicts
    __shared__ float Bs[32][64];
    int t  = threadIdx.x;
    int bm = blockIdx.x * 64;
    int bn = blockIdx.y * 64;
    int tx = t % 16, ty = t / 16;
    float acc[4][4] = {};
    int am0 = t / 8;            // 0..31
    int ak0 = (t % 8) * 4;      // 0..28 step 4
    int bk0 = t / 16;           // 0..15
    int bn0 = (t % 16) * 4;

    for (int k0 = 0; k0 < K; k0 += 32) {
        float4 a0 = make_float4(0.f, 0.f, 0.f, 0.f);
        float4 a1 = make_float4(0.f, 0.f, 0.f, 0.f);
        int r0 = bm + am0, r1 = bm + am0 + 32;
        if (r0 < M) a0 = *(const float4*)&A[r0 * K + k0 + ak0];
        if (r1 < M) a1 = *(const float4*)&A[r1 * K + k0 + ak0];
        float4 b0  = *(const float4*)&B[(k0 + bk0) * Nn + bn + bn0];
        float4 b1v = *(const float4*)&B[(k0 + bk0 + 16) * Nn + bn + bn0];
        __syncthreads();
        As[ak0 + 0][am0] = a0.x; As[ak0 + 1][am0] = a0.y;
        As[ak0 + 2][am0] = a0.z; As[ak0 + 3][am0] = a0.w;
        As[ak0 + 0][am0 + 32] = a1.x; As[ak0 + 1][am0 + 32] = a1.y;
        As[ak0 + 2][am0 + 32] = a1.z; As[ak0 + 3][am0 + 32] = a1.w;
        *(float4*)&Bs[bk0][bn0]      = b0;
        *(float4*)&Bs[bk0 + 16][bn0] = b1v;
        __syncthreads();
#pragma unroll
        for (int kk = 0; kk < 32; kk++) {
            float4 av = *(float4*)&As[kk][ty * 4];
            float4 bv = *(float4*)&Bs[kk][tx * 4];
            acc[0][0] += av.x * bv.x; acc[0][1] += av.x * bv.y;
            acc[0][2] += av.x * bv.z; acc[0][3] += av.x * bv.w;
            acc[1][0] += av.y * bv.x; acc[1][1] += av.y * bv.y;
            acc[1][2] += av.y * bv.z; acc[1][3] += av.y * bv.w;
            acc[2][0] += av.z * bv.x; acc[2][1] += av.z * bv.y;
            acc[2][2] += av.z * bv.z; acc[2][3] += av.z * bv.w;
            acc[3][0] += av.w * bv.x; acc[3][1] += av.w * bv.y;
            acc[3][2] += av.w * bv.z; acc[3][3] += av.w * bv.w;
        }
    }
#pragma unroll
    for (int i = 0; i < 4; i++) {
        int row = bm + ty * 4 + i;
        if (row < M) {
            float4 v = make_float4(acc[i][0], acc[i][1], acc[i][2], acc[i][3]);
            *(float4*)&C[row * Nn + bn + tx * 4] = v;
        }
    }
    // fused attention-score epilogue
    int head = blockIdx.y;
    float4 av = *(const float4*)&a_src[head * 64 + tx * 4];
    float4 dv = *(const float4*)&a_dst[head * 64 + tx * 4];
#pragma unroll
    for (int i = 0; i < 4; i++) {
        float ps = acc[i][0] * av.x + acc[i][1] * av.y + acc[i][2] * av.z + acc[i][3] * av.w;
        float pd = acc[i][0] * dv.x + acc[i][1] * dv.y + acc[i][2] * dv.z + acc[i][3] * dv.w;
#pragma unroll
        for (int off = 8; off >= 1; off >>= 1) {
            ps += __shfl_xor(ps, off);
            pd += __shfl_xor(pd, off);
        }
        int row = bm + ty * 4 + i;
        if (tx == 0 && row < M) {
            s_sc[row * H + head] = ps;
            d_sc[row * H + head] = pd;
        }
    }
}

// ---------------------------------------------------------------- GAT aggregate
// Wave per node: softmax over incoming edges + weighted feature sum + bias + ELU.
template <int H, int C>
__global__ __launch_bounds__(256) void agg_kernel(const float* __restrict__ hbuf,
                                                  const int* __restrict__ row_ptr,
                                                  const int* __restrict__ csr_src,
                                                  const float* __restrict__ s_sc,
                                                  const float* __restrict__ d_sc,
                                                  const float* __restrict__ bias,
                                                  float* __restrict__ out) {
    constexpr int HC = H * C;
    int w = threadIdx.x >> 6, lane = threadIdx.x & 63;
    int n = blockIdx.x * 4 + w;
    if (n >= NNODES) return;
    int r0 = row_ptr[n], deg = row_ptr[n + 1] - r0;

    float dsc[H];
#pragma unroll
    for (int h = 0; h < H; h++) dsc[h] = d_sc[n * H + h];

    // pass 1: exact segment max (lane-parallel over edges)
    float mx[H];
#pragma unroll
    for (int h = 0; h < H; h++) mx[h] = -INFINITY;
    for (int i = lane; i < deg; i += 64) {
        int s = csr_src[r0 + i];
#pragma unroll
        for (int h = 0; h < H; h++) {
            float e = s_sc[s * H + h] + dsc[h];
            e = (e >= 0.f) ? e : 0.2f * e;
            mx[h] = fmaxf(mx[h], e);
        }
    }
    for (int off = 32; off >= 1; off >>= 1)
#pragma unroll
        for (int h = 0; h < H; h++) mx[h] = fmaxf(mx[h], __shfl_xor(mx[h], off));

    // pass 2: exp/denom/feature accumulate, 64-edge chunks
    int  myh  = (lane * 4) / C;
    bool fact = (lane * 4) < HC;
    float acc[4] = {0.f, 0.f, 0.f, 0.f};
    float denom = 0.f;
    for (int base = 0; base < deg; base += 64) {
        int cnt = min(64, deg - base);
        int s_local = 0;
        float exl[H];
#pragma unroll
        for (int h = 0; h < H; h++) exl[h] = 0.f;
        if (lane < cnt) {
            s_local = csr_src[r0 + base + lane];
#pragma unroll
            for (int h = 0; h < H; h++) {
                float e = s_sc[s_local * H + h] + dsc[h];
                e = (e >= 0.f) ? e : 0.2f * e;
                exl[h] = expf(e - mx[h]);
            }
        }
        for (int j = 0; j < cnt; j++) {
            int sj = __shfl(s_local, j);
            float exj;
            if constexpr (H == 4) {
                float e0 = __shfl(exl[0], j), e1 = __shfl(exl[1], j);
                float e2 = __shfl(exl[2], j), e3 = __shfl(exl[3], j);
                exj = (myh == 0) ? e0 : (myh == 1) ? e1 : (myh == 2) ? e2 : e3;
            } else {
                exj = __shfl(exl[0], j);
            }
            denom += exj;
            if (fact) {
                float4 hv = *(const float4*)&hbuf[sj * HC + lane * 4];
                acc[0] += exj * hv.x; acc[1] += exj * hv.y;
                acc[2] += exj * hv.z; acc[3] += exj * hv.w;
            }
        }
    }
    if (fact) {
        float inv = 1.0f / (denom + 1e-16f);
#pragma unroll
        for (int k = 0; k < 4; k++) {
            float v = acc[k] * inv + bias[lane * 4 + k];
            v = (v > 0.f) ? v : expm1f(v);   // ELU
            out[n * HC + lane * 4 + k] = v;
        }
    }
}

// ---------------------------------------------------------------- batch pool
__global__ __launch_bounds__(256) void pool_kernel(const float* __restrict__ x,
                                                   const int* __restrict__ batch,
                                                   float* __restrict__ pooled,
                                                   float* __restrict__ cntb) {
    int b = blockIdx.x;
    int lo = 0, hi = NNODES;
    while (lo < hi) { int mid = (lo + hi) >> 1; if (batch[mid] < b) lo = mid + 1; else hi = mid; }
    int start = lo;
    hi = NNODES;
    while (lo < hi) { int mid = (lo + hi) >> 1; if (batch[mid] < b + 1) lo = mid + 1; else hi = mid; }
    int end = lo;

    int t = threadIdx.x;
    int c = t & 63, g = t >> 6;          // channel, node-stride group (4)
    float s = 0.f;
    for (int n = start + g; n < end; n += 4) s += x[n * 64 + c];
    __shared__ float buf[4][64];
    buf[g][c] = s;
    __syncthreads();
    if (t < 64) {
        pooled[b * 64 + t] = buf[0][t] + buf[1][t] + buf[2][t] + buf[3][t];
        if (t == 0) cntb[b] = (float)(end - start);
    }
}

// ---------------------------------------------------------------- MLP heads
// One block per batch element: emb in LDS, channel-split k-loops, LDS/shuffle
// reductions. Kills the 1-block dependent-global-load latency chain.
__global__ __launch_bounds__(256) void head_kernel(const float* __restrict__ pL,
                                                   const float* __restrict__ cL,
                                                   const float* __restrict__ pR,
                                                   const float* __restrict__ cR,
                                                   const float* __restrict__ w1a,
                                                   const float* __restrict__ b1a,
                                                   const float* __restrict__ w2a,
                                                   const float* __restrict__ b2a,
                                                   const float* __restrict__ w1b,
                                                   const float* __restrict__ b1b,
                                                   const float* __restrict__ w2b,
                                                   const float* __restrict__ b2b,
                                                   float* __restrict__ out) {
    int b = blockIdx.x;
    int t = threadIdx.x;
    __shared__ float emb[128];
    __shared__ float ph[4][64];
    __shared__ float h1[64];
    if (t < 64)        emb[t] = pL[b * 64 + t] / fmaxf(cL[b], 1.0f);
    else if (t < 128)  emb[t] = pR[b * 64 + (t - 64)] / fmaxf(cR[b], 1.0f);
    __syncthreads();
    int c = t & 63, g = t >> 6;       // channel, k-chunk

    // ---- fc1 head
    {
        float p = 0.f;
#pragma unroll
        for (int k = 0; k < 32; k++) p += emb[g * 32 + k] * w1a[(g * 32 + k) * 64 + c];
        ph[g][c] = p;
        __syncthreads();
        if (t < 64) h1[t] = fmaxf(ph[0][t] + ph[1][t] + ph[2][t] + ph[3][t] + b1a[t], 0.f);
        __syncthreads();
        if (t < 128) {
            int o = t >> 6, lane = t & 63;
            float q = h1[lane] * w2a[lane * 2 + o];
#pragma unroll
            for (int off = 32; off >= 1; off >>= 1) q += __shfl_xor(q, off);
            if (lane == 0) out[b * 2 + o] = q + b2a[o];
        }
        __syncthreads();
    }
    // ---- fc2 head
    {
        float p = 0.f;
#pragma unroll
        for (int k = 0; k < 32; k++) p += emb[g * 32 + k] * w1b[(g * 32 + k) * 64 + c];
        ph[g][c] = p;
        __syncthreads();
        if (t < 64) h1[t] = fmaxf(ph[0][t] + ph[1][t] + ph[2][t] + ph[3][t] + b1b[t], 0.f);
        __syncthreads();
        if (t < 128) {
            int o = t >> 6, lane = t & 63;
            float q = h1[lane] * w2b[lane * 2 + o];
#pragma unroll
            for (int off = 32; off >= 1; off >>= 1) q += __shfl_xor(q, off);
            if (lane == 0) out[128 + b * 2 + o] = q + b2b[o];
        }
    }
}

// ---------------------------------------------------------------- launcher
extern "C" void kernel_launch(void* const* d_in, const int* in_sizes, int n_in,
                              void* d_out, int out_size, void* d_ws, size_t ws_size,
                              hipStream_t stream) {
    const float* x_left   = (const float*)d_in[0];
    const float* x_right  = (const float*)d_in[1];
    const int*   ei_left  = (const int*)d_in[2];
    const int*   ei_right = (const int*)d_in[3];
    const int*   ba_left  = (const int*)d_in[4];
    const int*   ba_right = (const int*)d_in[5];
    const float* w1  = (const float*)d_in[6];
    const float* as1 = (const float*)d_in[7];
    const float* ad1 = (const float*)d_in[8];
    const float* b1  = (const float*)d_in[9];
    const float* w2  = (const float*)d_in[10];
    const float* as2 = (const float*)d_in[11];
    const float* ad2 = (const float*)d_in[12];
    const float* b2  = (const float*)d_in[13];
    const float* w3  = (const float*)d_in[14];
    const float* as3 = (const float*)d_in[15];
    const float* ad3 = (const float*)d_in[16];
    const float* b3  = (const float*)d_in[17];
    const float* f1w1 = (const float*)d_in[18];
    const float* f1b1 = (const float*)d_in[19];
    const float* f1w2 = (const float*)d_in[20];
    const float* f1b2 = (const float*)d_in[21];
    const float* f2w1 = (const float*)d_in[22];
    const float* f2b1 = (const float*)d_in[23];
    const float* f2w2 = (const float*)d_in[24];
    const float* f2b2 = (const float*)d_in[25];

    // workspace carve (256B aligned)
    char* w = (char*)d_ws;
    auto carve = [&](size_t bytes) {
        void* p = (void*)w;
        w += (bytes + 255) & ~(size_t)255;
        return p;
    };
    float* buf0    = (float*)carve((size_t)NNODES * 256 * 4);
    float* buf1    = (float*)carve((size_t)NNODES * 256 * 4);
    float* s_sc    = (float*)carve((size_t)NNODES * 4 * 4);
    float* d_sc    = (float*)carve((size_t)NNODES * 4 * 4);
    int*   cnt     = (int*)carve((size_t)NNODES * 4);
    int*   row_ptr = (int*)carve((size_t)(NNODES + 1) * 4);
    int*   fillp   = (int*)carve((size_t)NNODES * 4);
    int*   csr     = (int*)carve((size_t)EPRIME * 4);
    float* pooledL = (float*)carve(64 * 64 * 4);
    float* pooledR = (float*)carve(64 * 64 * 4);
    float* cntbL   = (float*)carve(64 * 4);
    float* cntbR   = (float*)carve(64 * 4);

    const int egrid = (EPRIME + 255) / 256;
    const int ngrid = (NNODES + 3) / 4;       // wave-per-node kernels
    const int mgrid = (NNODES + 63) / 64;     // gemm row tiles

    for (int side = 0; side < 2; side++) {
        const float* x_in  = side ? x_right  : x_left;
        const int*   ei    = side ? ei_right : ei_left;
        const int*   batch = side ? ba_right : ba_left;
        float* pooled = side ? pooledR : pooledL;
        float* cntb   = side ? cntbR   : cntbL;

        // CSR by dst (shared across the 3 layers)
        hipMemsetAsync(cnt, 0, (size_t)NNODES * 4, stream);
        count_kernel<<<egrid, 256, 0, stream>>>(ei, cnt);
        scan_kernel<<<1, 1024, 0, stream>>>(cnt, row_ptr, fillp);
        fill_kernel<<<egrid, 256, 0, stream>>>(ei, fillp, csr);

        // layer 1: x[N,128] @ w1[128,256] + fused scores
        gemm_kernel<<<dim3(mgrid, 4), 256, 0, stream>>>(x_in, w1, buf0, NNODES, 128, 256,
                                                        as1, ad1, s_sc, d_sc, 4);
        agg_kernel<4, 64><<<ngrid, 256, 0, stream>>>(buf0, row_ptr, csr, s_sc, d_sc, b1, buf1);

        // layer 2: buf1[N,256] @ w2[256,256] + fused scores
        gemm_kernel<<<dim3(mgrid, 4), 256, 0, stream>>>(buf1, w2, buf0, NNODES, 256, 256,
                                                        as2, ad2, s_sc, d_sc, 4);
        agg_kernel<4, 64><<<ngrid, 256, 0, stream>>>(buf0, row_ptr, csr, s_sc, d_sc, b2, buf1);

        // layer 3: buf1[N,256] @ w3[256,64], single head + fused scores
        gemm_kernel<<<dim3(mgrid, 1), 256, 0, stream>>>(buf1, w3, buf0, NNODES, 256, 64,
                                                        as3, ad3, s_sc, d_sc, 1);
        agg_kernel<1, 64><<<ngrid, 256, 0, stream>>>(buf0, row_ptr, csr, s_sc, d_sc, b3, buf1);

        // batch mean-pool: one block per batch slot, no atomics (batch sorted)
        pool_kernel<<<NBATCH, 256, 0, stream>>>(buf1, batch, pooled, cntb);
    }

    head_kernel<<<NBATCH, 256, 0, stream>>>(pooledL, cntbL, pooledR, cntbR,
                                            f1w1, f1b1, f1w2, f1b2,
                                            f2w1, f2b1, f2w2, f2b2,
                                            (float*)d_out);
}